// Round 13
// baseline (20843.744 us; speedup 1.0000x reference)
//
#include <hip/hip_runtime.h>

typedef __attribute__((ext_vector_type(8))) short s16x8;
typedef __attribute__((ext_vector_type(4))) short s16x4;
typedef __attribute__((ext_vector_type(4))) float f32x4;
typedef __attribute__((ext_vector_type(4))) unsigned short u16x4;

template<int V> struct IC { static constexpr int v = V; };

__device__ __forceinline__ unsigned short f2bf(float f){
  unsigned u = __float_as_uint(f);
  u += 0x7fffu + ((u >> 16) & 1u);   // RNE
  return (unsigned short)(u >> 16);
}

// x0 [16384,256] f32 -> XT [256,16384] bf16
__global__ void xpose_cvt(const float* __restrict__ src, unsigned short* __restrict__ dst){
  __shared__ float tile[64][65];
  const int R0 = blockIdx.x * 64;
  const int C0 = blockIdx.y * 64;
  const int t = threadIdx.x;
  #pragma unroll
  for (int i = 0; i < 16; ++i){
    int id = i * 256 + t; int r = id >> 6, c = id & 63;
    tile[r][c] = src[(size_t)(R0 + r) * 256 + (C0 + c)];
  }
  __syncthreads();
  #pragma unroll
  for (int i = 0; i < 16; ++i){
    int id = i * 256 + t; int c = id >> 6, r = id & 63;
    dst[(size_t)(C0 + c) * 16384 + (R0 + r)] = f2bf(tile[r][c]);
  }
}

__global__ void cvt_k(const float* __restrict__ src, unsigned short* __restrict__ dst, int n){
  int i = (blockIdx.x * 256 + threadIdx.x) * 4;
  if (i + 3 < n){
    f32x4 v = *(const f32x4*)(src + i);
    u16x4 o; o[0] = f2bf(v[0]); o[1] = f2bf(v[1]); o[2] = f2bf(v[2]); o[3] = f2bf(v[3]);
    *(u16x4*)(dst + i) = o;
  }
}

// ---- dedup chain: unique rows referenced by nodes_idx ----
__global__ void dedup_clear(int* flags, int* count){
  int i = blockIdx.x * 256 + threadIdx.x;
  if (i < 16384) flags[i] = 0;
  if (i == 0) *count = 0;
}
__global__ void dedup_mark(const int* __restrict__ idx, int* __restrict__ flags){
  int i = blockIdx.x * 256 + threadIdx.x;
  if (i < 8192) flags[idx[i]] = 1;
}
__global__ void dedup_compact(const int* __restrict__ flags, int* __restrict__ rank,
                              int* __restrict__ ulist, int* __restrict__ count){
  int i = blockIdx.x * 256 + threadIdx.x;
  if (i < 16384 && flags[i]){
    int r = atomicAdd(count, 1);
    rank[i] = r;
    ulist[r] = i;
  }
}
__global__ void dedup_remap(const int* __restrict__ idx, const int* __restrict__ rank,
                            int* __restrict__ gidx2){
  int i = blockIdx.x * 256 + threadIdx.x;
  if (i < 8192) gidx2[i] = rank[idx[i]];
}

// ---------------- Pipelined big GEMM: P[kc] = A @ X^T (split-K=4) ----------------
// NO vmcnt drain in the K-loop: reg-staged loads (private regs -> barrier does not
// require draining them), 2-deep prefetch, double-buffered LDS (96 KiB, 1 blk/CU),
// RAW s_barrier + lgkmcnt(0) only. The compiler inserts precise per-register vmcnt
// waits at the ds_write that consumes each load set, leaving newer prefetch in flight.
// BM=128/BN=256/BK=64, 512 thr (8 waves 2m x 4n, wave tile 64x64).
// Grid: xcd=b&7; kc=xcd>>1 (B-slice 2 MiB/XCD, L2-resident); mi=(xcd&1)*{64|32}+(b>>3).
// AMODE 0: A fp32, convert in-flight + persist bf16 to Aout (grid 512).
// AMODE 1: A bf16 (grid 512).  AMODE 2: A bf16 gathered via ulist, early-exit (grid 256).
template<int AMODE>
__global__ __launch_bounds__(512, 2)
void gemmP_k(const void* __restrict__ Asrc, const unsigned short* __restrict__ Bsrc,
             float* __restrict__ Pdst, unsigned short* __restrict__ Aout,
             const int* __restrict__ ulist, const int* __restrict__ pnuniq)
{
  __shared__ __align__(16) unsigned short Alds[2][128 * 64];
  __shared__ __align__(16) unsigned short Blds[2][256 * 64];

  const int tid  = threadIdx.x;
  const int lane = tid & 63;
  const int wv   = tid >> 6;
  const int wm   = wv >> 2;        // 0..1 (64 rows each)
  const int wn   = wv & 3;         // 0..3 (64 cols each)
  const int fr = lane & 15, fq = lane >> 4;

  const int b    = blockIdx.x;
  const int xcd  = b & 7;
  const int kc   = xcd >> 1;                    // 0..3
  const int mi   = (AMODE == 2) ? (((xcd & 1) << 5) + (b >> 3))
                                 : (((xcd & 1) << 6) + (b >> 3));
  const int row0 = mi * 128;
  const int kbase = kc * 4096;

  int nuniq = 0;
  if constexpr (AMODE == 2){
    nuniq = *pnuniq;
    if (row0 >= nuniq) return;     // block-uniform early exit before any barrier
  }

  const int rS = tid >> 3;         // 0..63 (staging row base)
  const int cS = tid & 7;          // 16B chunk (8 elems) within 64-elem k-slab

  // this thread's two A rows (tile rows rS and rS+64)
  size_t ar0, ar1;
  if constexpr (AMODE == 2){
    int j0 = row0 + rS, j1 = row0 + rS + 64;
    ar0 = (size_t)ulist[j0 < nuniq ? j0 : 0];
    ar1 = (size_t)ulist[j1 < nuniq ? j1 : 0];
  } else {
    ar0 = (size_t)(row0 + rS);
    ar1 = (size_t)(row0 + rS + 64);
  }

  f32x4 acc[4][4];
  #pragma unroll
  for (int m = 0; m < 4; ++m)
    #pragma unroll
    for (int n = 0; n < 4; ++n)
      acc[m][n] = f32x4{0.f, 0.f, 0.f, 0.f};

  f32x4 aF[2][4];    // AMODE 0: fp32 staging (2 sets in flight)
  s16x8 aB[2][2];    // AMODE 1/2: bf16 staging
  s16x8 bR[2][4];

  auto loadR = [&](int set, int k0){
    if constexpr (AMODE == 0){
      const float* p0 = (const float*)Asrc + ar0 * 16384 + k0 + cS * 8;
      const float* p1 = (const float*)Asrc + ar1 * 16384 + k0 + cS * 8;
      aF[set][0] = __builtin_nontemporal_load((const f32x4*)p0);
      aF[set][1] = __builtin_nontemporal_load((const f32x4*)(p0 + 4));
      aF[set][2] = __builtin_nontemporal_load((const f32x4*)p1);
      aF[set][3] = __builtin_nontemporal_load((const f32x4*)(p1 + 4));
    } else {
      aB[set][0] = __builtin_nontemporal_load(
        (const s16x8*)((const unsigned short*)Asrc + ar0 * 16384 + k0 + cS * 8));
      aB[set][1] = __builtin_nontemporal_load(
        (const s16x8*)((const unsigned short*)Asrc + ar1 * 16384 + k0 + cS * 8));
    }
    #pragma unroll
    for (int i = 0; i < 4; ++i)
      bR[set][i] = *(const s16x8*)(Bsrc + (size_t)(rS + i * 64) * 16384 + k0 + cS * 8);
  };

  auto writeL = [&](int set, int buf, int k0){
    s16x8 w0, w1;
    if constexpr (AMODE == 0){
      #pragma unroll
      for (int e = 0; e < 4; ++e){
        w0[e] = (short)f2bf(aF[set][0][e]); w0[e + 4] = (short)f2bf(aF[set][1][e]);
        w1[e] = (short)f2bf(aF[set][2][e]); w1[e + 4] = (short)f2bf(aF[set][3][e]);
      }
      __builtin_nontemporal_store(w0, (s16x8*)&Aout[ar0 * 16384 + k0 + cS * 8]);
      __builtin_nontemporal_store(w1, (s16x8*)&Aout[ar1 * 16384 + k0 + cS * 8]);
    } else {
      w0 = aB[set][0];
      w1 = aB[set][1];
    }
    // XOR-swizzled LDS layout (read back with same XOR). (rS+64)&7 == rS&7.
    *(s16x8*)&Alds[buf][rS * 64 + ((cS ^ (rS & 7)) * 8)] = w0;
    *(s16x8*)&Alds[buf][(rS + 64) * 64 + ((cS ^ (rS & 7)) * 8)] = w1;
    #pragma unroll
    for (int i = 0; i < 4; ++i){
      int r = rS + i * 64;
      *(s16x8*)&Blds[buf][r * 64 + ((cS ^ (r & 7)) * 8)] = bR[set][i];
    }
  };

  auto compute = [&](int buf){
    #pragma unroll
    for (int k = 0; k < 2; ++k){
      s16x8 af[4], bfr[4];
      const int c = k * 4 + fq;
      #pragma unroll
      for (int m = 0; m < 4; ++m){
        int row = wm * 64 + m * 16 + fr;
        af[m] = *(const s16x8*)&Alds[buf][row * 64 + ((c ^ (row & 7)) * 8)];
      }
      #pragma unroll
      for (int n = 0; n < 4; ++n){
        int col = wn * 64 + n * 16 + fr;
        bfr[n] = *(const s16x8*)&Blds[buf][col * 64 + ((c ^ (col & 7)) * 8)];
      }
      #pragma unroll
      for (int m = 0; m < 4; ++m)
        #pragma unroll
        for (int n = 0; n < 4; ++n)
          acc[m][n] = __builtin_amdgcn_mfma_f32_16x16x32_bf16(af[m], bfr[n], acc[m][n], 0, 0, 0);
    }
  };

  // prologue: set0=step0, set1=step1; LDS buf0 = step0
  loadR(0, kbase);
  loadR(1, kbase + 64);
  writeL(0, 0, kbase);
  asm volatile("s_waitcnt lgkmcnt(0)" ::: "memory");
  __builtin_amdgcn_s_barrier();
  __builtin_amdgcn_sched_barrier(0);

  #pragma unroll 1
  for (int s = 0; s < 64; ++s){
    if (s + 2 < 64) loadR(s & 1, kbase + (s + 2) * 64);        // prefetch depth 2
    compute(s & 1);                                            // LDS only, no vm deps
    if (s + 1 < 64) writeL((s + 1) & 1, (s + 1) & 1, kbase + (s + 1) * 64);
    asm volatile("s_waitcnt lgkmcnt(0)" ::: "memory");         // ds_writes visible
    __builtin_amdgcn_s_barrier();                              // raw: NO vmcnt drain
    __builtin_amdgcn_sched_barrier(0);
  }

  // epilogue: fp32 partial store (nt). C frag: col = lane&15, row = (lane>>4)*4 + j
  float* P = Pdst + (size_t)kc * 16384 * 256;
  #pragma unroll
  for (int m = 0; m < 4; ++m){
    int rowb = row0 + wm * 64 + m * 16 + fq * 4;
    #pragma unroll
    for (int n = 0; n < 4; ++n){
      int col = wn * 64 + n * 16 + fr;
      #pragma unroll
      for (int j = 0; j < 4; ++j)
        __builtin_nontemporal_store(acc[m][n][j], &P[(size_t)(rowb + j) * 256 + col]);
    }
  }
}

// ---------------- Small GEMM: C[M,BN] = A[M,Kd] @ B^T, BM=32 ----------------
// AMODE: 1 = A bf16 | 2 = A bf16 + gather | 3 = A = sum of 4 fp32 partials
// EPI: 1 = bias+relu bf16 TRANSPOSED | 2 = bias+relu bf16 row-major | 3 = bias+relu fp32
template<int BN, int AMODE, int EPI>
__global__ __launch_bounds__(512, 2)
void gemm_k(const void* __restrict__ Asrc, const unsigned short* __restrict__ Bsrc,
            const float* __restrict__ bias, const int* __restrict__ gidx,
            void* __restrict__ Cdst, const int M, const int Kd)
{
  constexpr int NF = BN / 64;
  constexpr int BITER = BN / 64;
  __shared__ __align__(16) unsigned short Alds[2][32 * 64];
  __shared__ __align__(16) unsigned short Blds[2][BN * 64];

  const int tid  = threadIdx.x;
  const int lane = tid & 63;
  const int wv   = tid >> 6;
  const int wm   = wv >> 2;
  const int wn   = wv & 3;
  const int row0 = blockIdx.x * 32;
  const int fr = lane & 15, fq = lane >> 4;

  const int rA = tid >> 4;
  const int cA = tid & 15;
  const int rB = tid >> 3;
  const int cB = tid & 7;

  size_t arow;
  if (AMODE == 2) arow = (size_t)gidx[row0 + rA];
  else            arow = (size_t)(row0 + rA);

  f32x4 acc[NF];
  #pragma unroll
  for (int n = 0; n < NF; ++n) acc[n] = f32x4{0.f, 0.f, 0.f, 0.f};

  f32x4 aP[2][4]; s16x4 aB[2]; s16x8 bRg[2][BITER];

  auto loadAB = [&](auto rsc, int k0){
    constexpr int RS = decltype(rsc)::v;
    if constexpr (AMODE == 3){
      #pragma unroll
      for (int q = 0; q < 4; ++q)
        aP[RS][q] = __builtin_nontemporal_load(
          (const f32x4*)((const float*)Asrc + (size_t)q * 16384 * 256 + arow * (size_t)Kd + (k0 + cA * 4)));
    } else {
      aB[RS] = *(const s16x4*)((const unsigned short*)Asrc + arow * (size_t)Kd + (k0 + cA * 4));
    }
    #pragma unroll
    for (int i = 0; i < BITER; ++i)
      bRg[RS][i] = *(const s16x8*)(Bsrc + (size_t)(rB + i * 64) * Kd + (k0 + cB * 8));
  };

  auto writeAB = [&](auto rsc, int buf){
    constexpr int RS = decltype(rsc)::v;
    s16x4 w;
    if constexpr (AMODE == 3){
      #pragma unroll
      for (int e = 0; e < 4; ++e)
        w[e] = (short)f2bf(aP[RS][0][e] + aP[RS][1][e] + aP[RS][2][e] + aP[RS][3][e]);
    } else {
      w = aB[RS];
    }
    *(s16x4*)&Alds[buf][rA * 64 + ((((cA >> 1) ^ (rA & 7)) * 8) + (cA & 1) * 4)] = w;
    #pragma unroll
    for (int i = 0; i < BITER; ++i){
      int r = rB + i * 64;
      *(s16x8*)&Blds[buf][r * 64 + ((cB ^ (r & 7)) * 8)] = bRg[RS][i];
    }
  };

  auto compute = [&](int buf){
    s16x8 af[2]; s16x8 bfr[NF][2];
    #pragma unroll
    for (int k = 0; k < 2; ++k){
      int row = wm * 16 + fr;
      int c = k * 4 + fq;
      af[k] = *(const s16x8*)&Alds[buf][row * 64 + ((c ^ (row & 7)) * 8)];
    }
    #pragma unroll
    for (int n = 0; n < NF; ++n)
      #pragma unroll
      for (int k = 0; k < 2; ++k){
        int col = wn * (BN / 4) + n * 16 + fr;
        int c = k * 4 + fq;
        bfr[n][k] = *(const s16x8*)&Blds[buf][col * 64 + ((c ^ (col & 7)) * 8)];
      }
    #pragma unroll
    for (int k = 0; k < 2; ++k)
      #pragma unroll
      for (int n = 0; n < NF; ++n)
        acc[n] = __builtin_amdgcn_mfma_f32_16x16x32_bf16(af[k], bfr[n][k], acc[n], 0, 0, 0);
  };

  const int nsteps = Kd / 64;
  loadAB(IC<0>{}, 0);
  loadAB(IC<1>{}, 64);
  writeAB(IC<0>{}, 0);
  __syncthreads();

  for (int s = 0; s < nsteps; s += 2){
    if (s + 2 < nsteps) loadAB(IC<0>{}, (s + 2) * 64);
    compute(0);
    if (s + 1 < nsteps) writeAB(IC<1>{}, 1);
    __syncthreads();
    if (s + 3 < nsteps) loadAB(IC<1>{}, (s + 3) * 64);
    compute(1);
    if (s + 2 < nsteps) writeAB(IC<0>{}, 0);
    __syncthreads();
  }

  {
    int rowb = row0 + wm * 16 + fq * 4;
    #pragma unroll
    for (int n = 0; n < NF; ++n){
      int col = wn * (BN / 4) + n * 16 + fr;
      f32x4 v = acc[n];
      float b = bias[col];
      if constexpr (EPI == 1){
        u16x4 w;
        #pragma unroll
        for (int j = 0; j < 4; ++j) w[j] = f2bf(fmaxf(v[j] + b, 0.f));
        *(u16x4*)((unsigned short*)Cdst + (size_t)col * M + rowb) = w;
      } else if constexpr (EPI == 2){
        unsigned short* o = (unsigned short*)Cdst;
        #pragma unroll
        for (int j = 0; j < 4; ++j) o[(size_t)(rowb + j) * BN + col] = f2bf(fmaxf(v[j] + b, 0.f));
      } else {
        float* o = (float*)Cdst;
        #pragma unroll
        for (int j = 0; j < 4; ++j) o[(size_t)(rowb + j) * BN + col] = fmaxf(v[j] + b, 0.f);
      }
    }
  }
}

// out[i] = softmax(encode[i] @ W2^T + b2), one wave per row
__global__ void mlp2_k(const float* __restrict__ enc, const float* __restrict__ W2,
                       const float* __restrict__ b2, float* __restrict__ out){
  int gw = (int)((blockIdx.x * blockDim.x + threadIdx.x) >> 6);
  int lane = threadIdx.x & 63;
  if (gw >= 8192) return;
  int c = lane & 15, q = lane >> 4;
  const float* e = enc + (size_t)gw * 128 + q * 32;
  const float* w = W2 + c * 128 + q * 32;
  float s = 0.f;
  #pragma unroll
  for (int k = 0; k < 32; ++k) s += e[k] * w[k];
  s += __shfl_xor(s, 16);
  s += __shfl_xor(s, 32);
  s += b2[c];
  float mx = s;
  #pragma unroll
  for (int d = 1; d < 16; d <<= 1) mx = fmaxf(mx, __shfl_xor(mx, d));
  float ex = __expf(s - mx);
  float sm = ex;
  #pragma unroll
  for (int d = 1; d < 16; d <<= 1) sm += __shfl_xor(sm, d);
  float r = ex / sm;
  if (q == 0) out[(size_t)gw * 16 + c] = r;
}

extern "C" void kernel_launch(void* const* d_in, const int* in_sizes, int n_in,
                              void* d_out, int out_size, void* d_ws, size_t ws_size,
                              hipStream_t stream) {
  const float* A  = (const float*)d_in[0];   // [16384,16384]
  const float* x0 = (const float*)d_in[1];   // [16384,256]
  const float* gw = (const float*)d_in[2];   // [3,256,256]
  const float* gb = (const float*)d_in[3];   // [3,256]
  const float* w1 = (const float*)d_in[4];   // [128,256]
  const float* b1 = (const float*)d_in[5];   // [128]
  const float* w2 = (const float*)d_in[6];   // [16,128]
  const float* b2 = (const float*)d_in[7];   // [16]
  const int*  idx = (const int*)d_in[8];     // [8192]
  float* out = (float*)d_out;

  char* ws = (char*)d_ws;
  unsigned short* Abf = (unsigned short*)ws;                        // 16384^2 bf16 (512 MiB)
  float*          P   = (float*)(ws + (512u << 20));                // 4 x 16384*256 f32 (64 MiB)
  unsigned short* xbT = (unsigned short*)(ws + (576u << 20));       // 256*16384 bf16 (8 MiB)
  unsigned short* x3b = (unsigned short*)(ws + (584u << 20));       // 8192*256 bf16
  unsigned short* wgb = (unsigned short*)(ws + (592u << 20));       // 3*256*256 bf16
  unsigned short* w1b = (unsigned short*)(ws + (592u << 20) + 3 * 65536 * 2); // 128*256 bf16
  int* flags = (int*)(ws + (600u << 20));                           // 16384 ints
  int* rank  = (int*)(ws + (600u << 20) + (64u << 10));             // 16384 ints
  int* ulist = (int*)(ws + (600u << 20) + (128u << 10));            // 8192 ints
  int* gidx2 = (int*)(ws + (600u << 20) + (160u << 10));            // 8192 ints
  int* ucnt  = (int*)(ws + (600u << 20) + (192u << 10));            // 1 int

  xpose_cvt<<<dim3(256, 4), 256, 0, stream>>>(x0, xbT);
  cvt_k<<<192, 256, 0, stream>>>(gw, wgb, 3 * 65536);
  cvt_k<<<32, 256, 0, stream>>>(w1, w1b, 128 * 256);
  dedup_clear<<<64, 256, 0, stream>>>(flags, ucnt);
  dedup_mark<<<32, 256, 0, stream>>>(idx, flags);
  dedup_compact<<<64, 256, 0, stream>>>(flags, rank, ulist, ucnt);
  dedup_remap<<<32, 256, 0, stream>>>(idx, rank, gidx2);

  // layer 0: P = A @ X (split-K=4, fp32 A converted + persisted to Abf)
  gemmP_k<0><<<512, 512, 0, stream>>>(A, xbT, P, Abf, nullptr, nullptr);
  gemm_k<256, 3, 1><<<512, 512, 0, stream>>>(P, wgb + 0 * 65536, gb + 0 * 256, nullptr, xbT, 16384, 256);
  // layer 1
  gemmP_k<1><<<512, 512, 0, stream>>>(Abf, xbT, P, nullptr, nullptr, nullptr);
  gemm_k<256, 3, 1><<<512, 512, 0, stream>>>(P, wgb + 1 * 65536, gb + 1 * 256, nullptr, xbT, 16384, 256);
  // layer 2: only unique gathered rows j -> P[.][j]
  gemmP_k<2><<<256, 512, 0, stream>>>(Abf, xbT, P, nullptr, ulist, ucnt);
  gemm_k<256, 3, 2><<<256, 512, 0, stream>>>(P, wgb + 2 * 65536, gb + 2 * 256, nullptr, x3b, 8192, 256);
  // encode = relu(x3b[rank[idx]] @ W1^T + b1) -> d_out fp32
  gemm_k<128, 2, 3><<<256, 512, 0, stream>>>(x3b, w1b, b1, gidx2, out, 8192, 256);
  // out = softmax(encode @ W2^T + b2)
  mlp2_k<<<2048, 256, 0, stream>>>(out, w2, b2, out + (size_t)8192 * 128);
}

// Round 14
// 777.548 us; speedup vs baseline: 26.8070x; 26.8070x over previous
//
#include <hip/hip_runtime.h>

typedef __attribute__((ext_vector_type(8))) short s16x8;
typedef __attribute__((ext_vector_type(4))) short s16x4;
typedef __attribute__((ext_vector_type(4))) float f32x4;
typedef __attribute__((ext_vector_type(4))) unsigned short u16x4;

template<int V> struct IC { static constexpr int v = V; };

__device__ __forceinline__ unsigned short f2bf(float f){
  unsigned u = __float_as_uint(f);
  u += 0x7fffu + ((u >> 16) & 1u);   // RNE
  return (unsigned short)(u >> 16);
}

// x0 [16384,256] f32 -> XT [256,16384] bf16
__global__ void xpose_cvt(const float* __restrict__ src, unsigned short* __restrict__ dst){
  __shared__ float tile[64][65];
  const int R0 = blockIdx.x * 64;
  const int C0 = blockIdx.y * 64;
  const int t = threadIdx.x;
  #pragma unroll
  for (int i = 0; i < 16; ++i){
    int id = i * 256 + t; int r = id >> 6, c = id & 63;
    tile[r][c] = src[(size_t)(R0 + r) * 256 + (C0 + c)];
  }
  __syncthreads();
  #pragma unroll
  for (int i = 0; i < 16; ++i){
    int id = i * 256 + t; int c = id >> 6, r = id & 63;
    dst[(size_t)(C0 + c) * 16384 + (R0 + r)] = f2bf(tile[r][c]);
  }
}

__global__ void cvt_k(const float* __restrict__ src, unsigned short* __restrict__ dst, int n){
  int i = (blockIdx.x * 256 + threadIdx.x) * 4;
  if (i + 3 < n){
    f32x4 v = *(const f32x4*)(src + i);
    u16x4 o; o[0] = f2bf(v[0]); o[1] = f2bf(v[1]); o[2] = f2bf(v[2]); o[3] = f2bf(v[3]);
    *(u16x4*)(dst + i) = o;
  }
}

// ---- dedup chain: unique rows referenced by nodes_idx ----
__global__ void dedup_clear(int* flags, int* count){
  int i = blockIdx.x * 256 + threadIdx.x;
  if (i < 16384) flags[i] = 0;
  if (i == 0) *count = 0;
}
__global__ void dedup_mark(const int* __restrict__ idx, int* __restrict__ flags){
  int i = blockIdx.x * 256 + threadIdx.x;
  if (i < 8192) flags[idx[i]] = 1;
}
__global__ void dedup_compact(const int* __restrict__ flags, int* __restrict__ rank,
                              int* __restrict__ ulist, int* __restrict__ count){
  int i = blockIdx.x * 256 + threadIdx.x;
  if (i < 16384 && flags[i]){
    int r = atomicAdd(count, 1);
    rank[i] = r;
    ulist[r] = i;
  }
}
__global__ void dedup_remap(const int* __restrict__ idx, const int* __restrict__ rank,
                            int* __restrict__ gidx2){
  int i = blockIdx.x * 256 + threadIdx.x;
  if (i < 8192) gidx2[i] = rank[idx[i]];
}

// ---------------- Pipelined big GEMM: P[kc] = A @ X^T (split-K=4) ----------------
// R13's no-vmcnt-drain pipeline REDONE with STATIC set indices (rule #20 fix):
// loadAB/writeAB take IC<0>/IC<1> compile-time sets (R4's proven codegen pattern),
// loop body written twice (s += 2). Barriers: lgkmcnt(0) + raw s_barrier +
// sched_barrier(0) -- NO vmcnt drain; reg-staged global loads stay in flight, the
// compiler inserts per-register vmcnt waits at the consuming ds_write/convert.
// BM=128/BN=256/BK=64, 512 thr (8 waves 2m x 4n), dbuf LDS 96 KiB (1 blk/CU).
// Grid: xcd=b&7; kc=xcd>>1 (B-slice 2 MiB/XCD, L2-resident); mi=(xcd&1)*{64|32}+(b>>3).
// AMODE 0: A fp32, convert in-flight + persist bf16 to Aout (grid 512).
// AMODE 1: A bf16 (grid 512).  AMODE 2: A bf16 gathered via ulist, early-exit (grid 256).
template<int AMODE>
__global__ __launch_bounds__(512, 2)
void gemmP_k(const void* __restrict__ Asrc, const unsigned short* __restrict__ Bsrc,
             float* __restrict__ Pdst, unsigned short* __restrict__ Aout,
             const int* __restrict__ ulist, const int* __restrict__ pnuniq)
{
  __shared__ __align__(16) unsigned short Alds[2][128 * 64];
  __shared__ __align__(16) unsigned short Blds[2][256 * 64];

  const int tid  = threadIdx.x;
  const int lane = tid & 63;
  const int wv   = tid >> 6;
  const int wm   = wv >> 2;        // 0..1 (64 rows each)
  const int wn   = wv & 3;         // 0..3 (64 cols each)
  const int fr = lane & 15, fq = lane >> 4;

  const int b    = blockIdx.x;
  const int xcd  = b & 7;
  const int kc   = xcd >> 1;                    // 0..3
  const int mi   = (AMODE == 2) ? (((xcd & 1) << 5) + (b >> 3))
                                 : (((xcd & 1) << 6) + (b >> 3));
  const int row0 = mi * 128;
  const int kbase = kc * 4096;

  int nuniq = 0;
  if constexpr (AMODE == 2){
    nuniq = *pnuniq;
    if (row0 >= nuniq) return;     // block-uniform early exit before any barrier
  }

  const int rS = tid >> 3;         // 0..63 (staging row base)
  const int cS = tid & 7;          // 16B chunk (8 elems) within 64-elem k-slab

  size_t ar0, ar1;
  if constexpr (AMODE == 2){
    int j0 = row0 + rS, j1 = row0 + rS + 64;
    ar0 = (size_t)ulist[j0 < nuniq ? j0 : 0];
    ar1 = (size_t)ulist[j1 < nuniq ? j1 : 0];
  } else {
    ar0 = (size_t)(row0 + rS);
    ar1 = (size_t)(row0 + rS + 64);
  }

  f32x4 acc[4][4];
  #pragma unroll
  for (int m = 0; m < 4; ++m)
    #pragma unroll
    for (int n = 0; n < 4; ++n)
      acc[m][n] = f32x4{0.f, 0.f, 0.f, 0.f};

  // two STATICALLY-indexed staging sets (IC<> pattern -> registers, not scratch)
  f32x4 aF[2][4]; s16x8 aB[2][2]; s16x8 bR[2][4];

  auto loadAB = [&](auto setc, int k0){
    constexpr int S = decltype(setc)::v;
    if constexpr (AMODE == 0){
      const float* p0 = (const float*)Asrc + ar0 * 16384 + k0 + cS * 8;
      const float* p1 = (const float*)Asrc + ar1 * 16384 + k0 + cS * 8;
      aF[S][0] = __builtin_nontemporal_load((const f32x4*)p0);
      aF[S][1] = __builtin_nontemporal_load((const f32x4*)(p0 + 4));
      aF[S][2] = __builtin_nontemporal_load((const f32x4*)p1);
      aF[S][3] = __builtin_nontemporal_load((const f32x4*)(p1 + 4));
    } else {
      aB[S][0] = __builtin_nontemporal_load(
        (const s16x8*)((const unsigned short*)Asrc + ar0 * 16384 + k0 + cS * 8));
      aB[S][1] = __builtin_nontemporal_load(
        (const s16x8*)((const unsigned short*)Asrc + ar1 * 16384 + k0 + cS * 8));
    }
    #pragma unroll
    for (int i = 0; i < 4; ++i)
      bR[S][i] = *(const s16x8*)(Bsrc + (size_t)(rS + i * 64) * 16384 + k0 + cS * 8);
  };

  auto writeAB = [&](auto setc, int buf, int k0){
    constexpr int S = decltype(setc)::v;
    s16x8 w0, w1;
    if constexpr (AMODE == 0){
      #pragma unroll
      for (int e = 0; e < 4; ++e){
        w0[e] = (short)f2bf(aF[S][0][e]); w0[e + 4] = (short)f2bf(aF[S][1][e]);
        w1[e] = (short)f2bf(aF[S][2][e]); w1[e + 4] = (short)f2bf(aF[S][3][e]);
      }
      __builtin_nontemporal_store(w0, (s16x8*)&Aout[ar0 * 16384 + k0 + cS * 8]);
      __builtin_nontemporal_store(w1, (s16x8*)&Aout[ar1 * 16384 + k0 + cS * 8]);
    } else {
      w0 = aB[S][0];
      w1 = aB[S][1];
    }
    *(s16x8*)&Alds[buf][rS * 64 + ((cS ^ (rS & 7)) * 8)] = w0;
    *(s16x8*)&Alds[buf][(rS + 64) * 64 + ((cS ^ (rS & 7)) * 8)] = w1;
    #pragma unroll
    for (int i = 0; i < 4; ++i){
      int r = rS + i * 64;
      *(s16x8*)&Blds[buf][r * 64 + ((cS ^ (r & 7)) * 8)] = bR[S][i];
    }
  };

  auto compute = [&](int buf){
    #pragma unroll
    for (int k = 0; k < 2; ++k){
      s16x8 af[4], bfr[4];
      const int c = k * 4 + fq;
      #pragma unroll
      for (int m = 0; m < 4; ++m){
        int row = wm * 64 + m * 16 + fr;
        af[m] = *(const s16x8*)&Alds[buf][row * 64 + ((c ^ (row & 7)) * 8)];
      }
      #pragma unroll
      for (int n = 0; n < 4; ++n){
        int col = wn * 64 + n * 16 + fr;
        bfr[n] = *(const s16x8*)&Blds[buf][col * 64 + ((c ^ (col & 7)) * 8)];
      }
      #pragma unroll
      for (int m = 0; m < 4; ++m)
        #pragma unroll
        for (int n = 0; n < 4; ++n)
          acc[m][n] = __builtin_amdgcn_mfma_f32_16x16x32_bf16(af[m], bfr[n], acc[m][n], 0, 0, 0);
    }
  };

  #define PIPE_BARRIER() do {                                  \
    asm volatile("s_waitcnt lgkmcnt(0)" ::: "memory");         \
    __builtin_amdgcn_s_barrier();                              \
    __builtin_amdgcn_sched_barrier(0);                         \
  } while (0)

  // prologue: set0 = step0, set1 = step1; LDS buf0 = step0
  loadAB(IC<0>{}, kbase);
  loadAB(IC<1>{}, kbase + 64);
  writeAB(IC<0>{}, 0, kbase);
  PIPE_BARRIER();

  #pragma unroll 1
  for (int s = 0; s < 64; s += 2){
    // half-step A: compute buf0 (step s); stage step s+1 into buf1; prefetch s+2 into set0
    if (s + 2 < 64) loadAB(IC<0>{}, kbase + (s + 2) * 64);
    compute(0);
    if (s + 1 < 64) writeAB(IC<1>{}, 1, kbase + (s + 1) * 64);
    PIPE_BARRIER();
    // half-step B: compute buf1 (step s+1); stage s+2 into buf0; prefetch s+3 into set1
    if (s + 3 < 64) loadAB(IC<1>{}, kbase + (s + 3) * 64);
    if (s + 1 < 64) compute(1);
    if (s + 2 < 64) writeAB(IC<0>{}, 0, kbase + (s + 2) * 64);
    PIPE_BARRIER();
  }
  #undef PIPE_BARRIER

  // epilogue: fp32 partial store (nt). C frag: col = lane&15, row = (lane>>4)*4 + j
  float* P = Pdst + (size_t)kc * 16384 * 256;
  #pragma unroll
  for (int m = 0; m < 4; ++m){
    int rowb = row0 + wm * 64 + m * 16 + fq * 4;
    #pragma unroll
    for (int n = 0; n < 4; ++n){
      int col = wn * 64 + n * 16 + fr;
      #pragma unroll
      for (int j = 0; j < 4; ++j)
        __builtin_nontemporal_store(acc[m][n][j], &P[(size_t)(rowb + j) * 256 + col]);
    }
  }
}

// ---------------- Small GEMM: C[M,BN] = A[M,Kd] @ B^T, BM=32 ----------------
// AMODE: 1 = A bf16 | 2 = A bf16 + gather | 3 = A = sum of 4 fp32 partials
// EPI: 1 = bias+relu bf16 TRANSPOSED | 2 = bias+relu bf16 row-major | 3 = bias+relu fp32
template<int BN, int AMODE, int EPI>
__global__ __launch_bounds__(512, 2)
void gemm_k(const void* __restrict__ Asrc, const unsigned short* __restrict__ Bsrc,
            const float* __restrict__ bias, const int* __restrict__ gidx,
            void* __restrict__ Cdst, const int M, const int Kd)
{
  constexpr int NF = BN / 64;
  constexpr int BITER = BN / 64;
  __shared__ __align__(16) unsigned short Alds[2][32 * 64];
  __shared__ __align__(16) unsigned short Blds[2][BN * 64];

  const int tid  = threadIdx.x;
  const int lane = tid & 63;
  const int wv   = tid >> 6;
  const int wm   = wv >> 2;
  const int wn   = wv & 3;
  const int row0 = blockIdx.x * 32;
  const int fr = lane & 15, fq = lane >> 4;

  const int rA = tid >> 4;
  const int cA = tid & 15;
  const int rB = tid >> 3;
  const int cB = tid & 7;

  size_t arow;
  if (AMODE == 2) arow = (size_t)gidx[row0 + rA];
  else            arow = (size_t)(row0 + rA);

  f32x4 acc[NF];
  #pragma unroll
  for (int n = 0; n < NF; ++n) acc[n] = f32x4{0.f, 0.f, 0.f, 0.f};

  f32x4 aP[2][4]; s16x4 aB[2]; s16x8 bRg[2][BITER];

  auto loadAB = [&](auto rsc, int k0){
    constexpr int RS = decltype(rsc)::v;
    if constexpr (AMODE == 3){
      #pragma unroll
      for (int q = 0; q < 4; ++q)
        aP[RS][q] = __builtin_nontemporal_load(
          (const f32x4*)((const float*)Asrc + (size_t)q * 16384 * 256 + arow * (size_t)Kd + (k0 + cA * 4)));
    } else {
      aB[RS] = *(const s16x4*)((const unsigned short*)Asrc + arow * (size_t)Kd + (k0 + cA * 4));
    }
    #pragma unroll
    for (int i = 0; i < BITER; ++i)
      bRg[RS][i] = *(const s16x8*)(Bsrc + (size_t)(rB + i * 64) * Kd + (k0 + cB * 8));
  };

  auto writeAB = [&](auto rsc, int buf){
    constexpr int RS = decltype(rsc)::v;
    s16x4 w;
    if constexpr (AMODE == 3){
      #pragma unroll
      for (int e = 0; e < 4; ++e)
        w[e] = (short)f2bf(aP[RS][0][e] + aP[RS][1][e] + aP[RS][2][e] + aP[RS][3][e]);
    } else {
      w = aB[RS];
    }
    *(s16x4*)&Alds[buf][rA * 64 + ((((cA >> 1) ^ (rA & 7)) * 8) + (cA & 1) * 4)] = w;
    #pragma unroll
    for (int i = 0; i < BITER; ++i){
      int r = rB + i * 64;
      *(s16x8*)&Blds[buf][r * 64 + ((cB ^ (r & 7)) * 8)] = bRg[RS][i];
    }
  };

  auto compute = [&](int buf){
    s16x8 af[2]; s16x8 bfr[NF][2];
    #pragma unroll
    for (int k = 0; k < 2; ++k){
      int row = wm * 16 + fr;
      int c = k * 4 + fq;
      af[k] = *(const s16x8*)&Alds[buf][row * 64 + ((c ^ (row & 7)) * 8)];
    }
    #pragma unroll
    for (int n = 0; n < NF; ++n)
      #pragma unroll
      for (int k = 0; k < 2; ++k){
        int col = wn * (BN / 4) + n * 16 + fr;
        int c = k * 4 + fq;
        bfr[n][k] = *(const s16x8*)&Blds[buf][col * 64 + ((c ^ (col & 7)) * 8)];
      }
    #pragma unroll
    for (int k = 0; k < 2; ++k)
      #pragma unroll
      for (int n = 0; n < NF; ++n)
        acc[n] = __builtin_amdgcn_mfma_f32_16x16x32_bf16(af[k], bfr[n][k], acc[n], 0, 0, 0);
  };

  const int nsteps = Kd / 64;
  loadAB(IC<0>{}, 0);
  loadAB(IC<1>{}, 64);
  writeAB(IC<0>{}, 0);
  __syncthreads();

  for (int s = 0; s < nsteps; s += 2){
    if (s + 2 < nsteps) loadAB(IC<0>{}, (s + 2) * 64);
    compute(0);
    if (s + 1 < nsteps) writeAB(IC<1>{}, 1);
    __syncthreads();
    if (s + 3 < nsteps) loadAB(IC<1>{}, (s + 3) * 64);
    compute(1);
    if (s + 2 < nsteps) writeAB(IC<0>{}, 0);
    __syncthreads();
  }

  {
    int rowb = row0 + wm * 16 + fq * 4;
    #pragma unroll
    for (int n = 0; n < NF; ++n){
      int col = wn * (BN / 4) + n * 16 + fr;
      f32x4 v = acc[n];
      float b = bias[col];
      if constexpr (EPI == 1){
        u16x4 w;
        #pragma unroll
        for (int j = 0; j < 4; ++j) w[j] = f2bf(fmaxf(v[j] + b, 0.f));
        *(u16x4*)((unsigned short*)Cdst + (size_t)col * M + rowb) = w;
      } else if constexpr (EPI == 2){
        unsigned short* o = (unsigned short*)Cdst;
        #pragma unroll
        for (int j = 0; j < 4; ++j) o[(size_t)(rowb + j) * BN + col] = f2bf(fmaxf(v[j] + b, 0.f));
      } else {
        float* o = (float*)Cdst;
        #pragma unroll
        for (int j = 0; j < 4; ++j) o[(size_t)(rowb + j) * BN + col] = fmaxf(v[j] + b, 0.f);
      }
    }
  }
}

// out[i] = softmax(encode[i] @ W2^T + b2), one wave per row
__global__ void mlp2_k(const float* __restrict__ enc, const float* __restrict__ W2,
                       const float* __restrict__ b2, float* __restrict__ out){
  int gw = (int)((blockIdx.x * blockDim.x + threadIdx.x) >> 6);
  int lane = threadIdx.x & 63;
  if (gw >= 8192) return;
  int c = lane & 15, q = lane >> 4;
  const float* e = enc + (size_t)gw * 128 + q * 32;
  const float* w = W2 + c * 128 + q * 32;
  float s = 0.f;
  #pragma unroll
  for (int k = 0; k < 32; ++k) s += e[k] * w[k];
  s += __shfl_xor(s, 16);
  s += __shfl_xor(s, 32);
  s += b2[c];
  float mx = s;
  #pragma unroll
  for (int d = 1; d < 16; d <<= 1) mx = fmaxf(mx, __shfl_xor(mx, d));
  float ex = __expf(s - mx);
  float sm = ex;
  #pragma unroll
  for (int d = 1; d < 16; d <<= 1) sm += __shfl_xor(sm, d);
  float r = ex / sm;
  if (q == 0) out[(size_t)gw * 16 + c] = r;
}

extern "C" void kernel_launch(void* const* d_in, const int* in_sizes, int n_in,
                              void* d_out, int out_size, void* d_ws, size_t ws_size,
                              hipStream_t stream) {
  const float* A  = (const float*)d_in[0];   // [16384,16384]
  const float* x0 = (const float*)d_in[1];   // [16384,256]
  const float* gw = (const float*)d_in[2];   // [3,256,256]
  const float* gb = (const float*)d_in[3];   // [3,256]
  const float* w1 = (const float*)d_in[4];   // [128,256]
  const float* b1 = (const float*)d_in[5];   // [128]
  const float* w2 = (const float*)d_in[6];   // [16,128]
  const float* b2 = (const float*)d_in[7];   // [16]
  const int*  idx = (const int*)d_in[8];     // [8192]
  float* out = (float*)d_out;

  char* ws = (char*)d_ws;
  unsigned short* Abf = (unsigned short*)ws;                        // 16384^2 bf16 (512 MiB)
  float*          P   = (float*)(ws + (512u << 20));                // 4 x 16384*256 f32 (64 MiB)
  unsigned short* xbT = (unsigned short*)(ws + (576u << 20));       // 256*16384 bf16 (8 MiB)
  unsigned short* x3b = (unsigned short*)(ws + (584u << 20));       // 8192*256 bf16
  unsigned short* wgb = (unsigned short*)(ws + (592u << 20));       // 3*256*256 bf16
  unsigned short* w1b = (unsigned short*)(ws + (592u << 20) + 3 * 65536 * 2); // 128*256 bf16
  int* flags = (int*)(ws + (600u << 20));                           // 16384 ints
  int* rank  = (int*)(ws + (600u << 20) + (64u << 10));             // 16384 ints
  int* ulist = (int*)(ws + (600u << 20) + (128u << 10));            // 8192 ints
  int* gidx2 = (int*)(ws + (600u << 20) + (160u << 10));            // 8192 ints
  int* ucnt  = (int*)(ws + (600u << 20) + (192u << 10));            // 1 int

  xpose_cvt<<<dim3(256, 4), 256, 0, stream>>>(x0, xbT);
  cvt_k<<<192, 256, 0, stream>>>(gw, wgb, 3 * 65536);
  cvt_k<<<32, 256, 0, stream>>>(w1, w1b, 128 * 256);
  dedup_clear<<<64, 256, 0, stream>>>(flags, ucnt);
  dedup_mark<<<32, 256, 0, stream>>>(idx, flags);
  dedup_compact<<<64, 256, 0, stream>>>(flags, rank, ulist, ucnt);
  dedup_remap<<<32, 256, 0, stream>>>(idx, rank, gidx2);

  // layer 0: P = A @ X (split-K=4, fp32 A converted + persisted to Abf)
  gemmP_k<0><<<512, 512, 0, stream>>>(A, xbT, P, Abf, nullptr, nullptr);
  gemm_k<256, 3, 1><<<512, 512, 0, stream>>>(P, wgb + 0 * 65536, gb + 0 * 256, nullptr, xbT, 16384, 256);
  // layer 1
  gemmP_k<1><<<512, 512, 0, stream>>>(Abf, xbT, P, nullptr, nullptr, nullptr);
  gemm_k<256, 3, 1><<<512, 512, 0, stream>>>(P, wgb + 1 * 65536, gb + 1 * 256, nullptr, xbT, 16384, 256);
  // layer 2: only unique gathered rows j -> P[.][j]
  gemmP_k<2><<<256, 512, 0, stream>>>(Abf, xbT, P, nullptr, ulist, ucnt);
  gemm_k<256, 3, 2><<<256, 512, 0, stream>>>(P, wgb + 2 * 65536, gb + 2 * 256, nullptr, x3b, 8192, 256);
  // encode = relu(x3b[rank[idx]] @ W1^T + b1) -> d_out fp32
  gemm_k<128, 2, 3><<<256, 512, 0, stream>>>(x3b, w1b, b1, gidx2, out, 8192, 256);
  // out = softmax(encode @ W2^T + b2)
  mlp2_k<<<2048, 256, 0, stream>>>(out, w2, b2, out + (size_t)8192 * 128);
}

// Round 15
// 767.874 us; speedup vs baseline: 27.1448x; 1.0126x over previous
//
#include <hip/hip_runtime.h>

typedef __attribute__((ext_vector_type(8))) short s16x8;
typedef __attribute__((ext_vector_type(4))) short s16x4;
typedef __attribute__((ext_vector_type(4))) float f32x4;
typedef __attribute__((ext_vector_type(4))) unsigned short u16x4;

template<int V> struct IC { static constexpr int v = V; };

__device__ __forceinline__ unsigned short f2bf(float f){
  unsigned u = __float_as_uint(f);
  u += 0x7fffu + ((u >> 16) & 1u);   // RNE
  return (unsigned short)(u >> 16);
}

// x0 [16384,256] f32 -> XT [256,16384] bf16
__global__ void xpose_cvt(const float* __restrict__ src, unsigned short* __restrict__ dst){
  __shared__ float tile[64][65];
  const int R0 = blockIdx.x * 64;
  const int C0 = blockIdx.y * 64;
  const int t = threadIdx.x;
  #pragma unroll
  for (int i = 0; i < 16; ++i){
    int id = i * 256 + t; int r = id >> 6, c = id & 63;
    tile[r][c] = src[(size_t)(R0 + r) * 256 + (C0 + c)];
  }
  __syncthreads();
  #pragma unroll
  for (int i = 0; i < 16; ++i){
    int id = i * 256 + t; int c = id >> 6, r = id & 63;
    dst[(size_t)(C0 + c) * 16384 + (R0 + r)] = f2bf(tile[r][c]);
  }
}

// merged weight conversion: gw (3*256*256) -> wgb, w1 (128*256) -> w1b
__global__ void cvt2_k(const float* __restrict__ gw, unsigned short* __restrict__ wgb,
                       const float* __restrict__ w1, unsigned short* __restrict__ w1b){
  int i = (blockIdx.x * 256 + threadIdx.x) * 4;
  const int n0 = 3 * 65536;
  if (i < n0){
    f32x4 v = *(const f32x4*)(gw + i);
    u16x4 o; o[0] = f2bf(v[0]); o[1] = f2bf(v[1]); o[2] = f2bf(v[2]); o[3] = f2bf(v[3]);
    *(u16x4*)(wgb + i) = o;
  } else {
    int j = i - n0;
    if (j < 128 * 256){
      f32x4 v = *(const f32x4*)(w1 + j);
      u16x4 o; o[0] = f2bf(v[0]); o[1] = f2bf(v[1]); o[2] = f2bf(v[2]); o[3] = f2bf(v[3]);
      *(u16x4*)(w1b + j) = o;
    }
  }
}

// single-block dedup: flags+scan+compact+remap all in LDS (replaces 4 kernels)
__global__ __launch_bounds__(1024)
void dedup_all(const int* __restrict__ idx, int* __restrict__ ulist,
               int* __restrict__ gidx2, int* __restrict__ ucnt){
  __shared__ unsigned char flags[16384];
  __shared__ unsigned short rank16[16384];
  __shared__ int wsum[16];
  const int t = threadIdx.x;
  #pragma unroll
  for (int i = 0; i < 16; ++i) flags[t + i * 1024] = 0;
  __syncthreads();
  for (int i = t; i < 8192; i += 1024) flags[idx[i]] = 1;   // racing stores of 1: benign
  __syncthreads();
  const int base = t * 16;
  int cnt = 0;
  #pragma unroll
  for (int i = 0; i < 16; ++i) cnt += flags[base + i];
  int lane = t & 63, wv = t >> 6;
  int inc = cnt;
  #pragma unroll
  for (int d = 1; d < 64; d <<= 1){
    int v = __shfl_up(inc, d);
    if (lane >= d) inc += v;
  }
  if (lane == 63) wsum[wv] = inc;
  __syncthreads();
  int woff = 0;
  for (int w = 0; w < wv; ++w) woff += wsum[w];
  int r = woff + inc - cnt;          // exclusive prefix
  #pragma unroll
  for (int i = 0; i < 16; ++i){
    if (flags[base + i]){ rank16[base + i] = (unsigned short)r; ulist[r] = base + i; ++r; }
  }
  if (t == 1023) *ucnt = woff + inc;
  __syncthreads();
  for (int i = t; i < 8192; i += 1024) gidx2[i] = (int)rank16[idx[i]];
}

// ---------------- Pipelined big GEMM: P = A @ X^T (split-K=4, P interleaved) ----------------
// R14 no-vmcnt-drain pipeline. P layout: P[row][kc][64] (kc INNER) so consumers read a
// row's 4 partials from one 4KB page. bf16 modes use 4 register sets with K-PAIR issue:
// loads for steps s+2,s+3 go back-to-back -> 256B contiguous per A-row per DRAM burst
// (halves page activates; the R4-R14 3.5TB/s plateau is activate-limited, 128B/row/step).
// BM=128/BN=256/BK=64, 512 thr (8 waves 2m x 4n), dbuf LDS 96 KiB (1 blk/CU).
// Grid: xcd=b&7; kc=xcd>>1 (B-slice 2 MiB/XCD L2-resident); mi=(xcd&1)*{64|32}+(b>>3).
// AMODE 0: A fp32 (256B/row already), 2-set R14 loop, convert + persist bf16 to Aout.
// AMODE 1: A bf16, 4-set pair-issue (grid 512). AMODE 2: + gather via ulist (grid 256).
template<int AMODE>
__global__ __launch_bounds__(512, 2)
void gemmP_k(const void* __restrict__ Asrc, const unsigned short* __restrict__ Bsrc,
             float* __restrict__ Pdst, unsigned short* __restrict__ Aout,
             const int* __restrict__ ulist, const int* __restrict__ pnuniq)
{
  __shared__ __align__(16) unsigned short Alds[2][128 * 64];
  __shared__ __align__(16) unsigned short Blds[2][256 * 64];

  const int tid  = threadIdx.x;
  const int lane = tid & 63;
  const int wv   = tid >> 6;
  const int wm   = wv >> 2;        // 0..1 (64 rows each)
  const int wn   = wv & 3;         // 0..3 (64 cols each)
  const int fr = lane & 15, fq = lane >> 4;

  const int b    = blockIdx.x;
  const int xcd  = b & 7;
  const int kc   = xcd >> 1;                    // 0..3
  const int mi   = (AMODE == 2) ? (((xcd & 1) << 5) + (b >> 3))
                                 : (((xcd & 1) << 6) + (b >> 3));
  const int row0 = mi * 128;
  const int kbase = kc * 4096;

  int nuniq = 0;
  if constexpr (AMODE == 2){
    nuniq = *pnuniq;
    if (row0 >= nuniq) return;     // block-uniform early exit before any barrier
  }

  const int rS = tid >> 3;         // 0..63 (staging row base)
  const int cS = tid & 7;          // 16B chunk within 64-elem k-slab

  size_t ar0, ar1;
  if constexpr (AMODE == 2){
    int j0 = row0 + rS, j1 = row0 + rS + 64;
    ar0 = (size_t)ulist[j0 < nuniq ? j0 : 0];
    ar1 = (size_t)ulist[j1 < nuniq ? j1 : 0];
  } else {
    ar0 = (size_t)(row0 + rS);
    ar1 = (size_t)(row0 + rS + 64);
  }

  f32x4 acc[4][4];
  #pragma unroll
  for (int m = 0; m < 4; ++m)
    #pragma unroll
    for (int n = 0; n < 4; ++n)
      acc[m][n] = f32x4{0.f, 0.f, 0.f, 0.f};

  // statically-indexed staging sets (IC<> -> registers, rule #20)
  f32x4 aF[2][4];    // AMODE 0 (2 sets)
  s16x8 aB[4][2];    // AMODE 1/2 (4 sets)
  s16x8 bR[4][4];

  auto loadA = [&](auto setc, int k0){
    constexpr int S = decltype(setc)::v;
    if constexpr (AMODE == 0){
      const float* p0 = (const float*)Asrc + ar0 * 16384 + k0 + cS * 8;
      const float* p1 = (const float*)Asrc + ar1 * 16384 + k0 + cS * 8;
      aF[S][0] = __builtin_nontemporal_load((const f32x4*)p0);
      aF[S][1] = __builtin_nontemporal_load((const f32x4*)(p0 + 4));
      aF[S][2] = __builtin_nontemporal_load((const f32x4*)p1);
      aF[S][3] = __builtin_nontemporal_load((const f32x4*)(p1 + 4));
    } else {
      aB[S][0] = __builtin_nontemporal_load(
        (const s16x8*)((const unsigned short*)Asrc + ar0 * 16384 + k0 + cS * 8));
      aB[S][1] = __builtin_nontemporal_load(
        (const s16x8*)((const unsigned short*)Asrc + ar1 * 16384 + k0 + cS * 8));
    }
  };
  auto loadB = [&](auto setc, int k0){
    constexpr int S = decltype(setc)::v;
    #pragma unroll
    for (int i = 0; i < 4; ++i)
      bR[S][i] = *(const s16x8*)(Bsrc + (size_t)(rS + i * 64) * 16384 + k0 + cS * 8);
  };

  auto writeAB = [&](auto setc, int buf, int k0){
    constexpr int S = decltype(setc)::v;
    s16x8 w0, w1;
    if constexpr (AMODE == 0){
      constexpr int S2 = (S < 2) ? S : 0;
      #pragma unroll
      for (int e = 0; e < 4; ++e){
        w0[e] = (short)f2bf(aF[S2][0][e]); w0[e + 4] = (short)f2bf(aF[S2][1][e]);
        w1[e] = (short)f2bf(aF[S2][2][e]); w1[e + 4] = (short)f2bf(aF[S2][3][e]);
      }
      __builtin_nontemporal_store(w0, (s16x8*)&Aout[ar0 * 16384 + k0 + cS * 8]);
      __builtin_nontemporal_store(w1, (s16x8*)&Aout[ar1 * 16384 + k0 + cS * 8]);
    } else {
      w0 = aB[S][0];
      w1 = aB[S][1];
    }
    *(s16x8*)&Alds[buf][rS * 64 + ((cS ^ (rS & 7)) * 8)] = w0;
    *(s16x8*)&Alds[buf][(rS + 64) * 64 + ((cS ^ (rS & 7)) * 8)] = w1;
    #pragma unroll
    for (int i = 0; i < 4; ++i){
      int r = rS + i * 64;
      *(s16x8*)&Blds[buf][r * 64 + ((cS ^ (r & 7)) * 8)] = bR[S][i];
    }
  };

  auto compute = [&](int buf){
    #pragma unroll
    for (int k = 0; k < 2; ++k){
      s16x8 af[4], bfr[4];
      const int c = k * 4 + fq;
      #pragma unroll
      for (int m = 0; m < 4; ++m){
        int row = wm * 64 + m * 16 + fr;
        af[m] = *(const s16x8*)&Alds[buf][row * 64 + ((c ^ (row & 7)) * 8)];
      }
      #pragma unroll
      for (int n = 0; n < 4; ++n){
        int col = wn * 64 + n * 16 + fr;
        bfr[n] = *(const s16x8*)&Blds[buf][col * 64 + ((c ^ (col & 7)) * 8)];
      }
      #pragma unroll
      for (int m = 0; m < 4; ++m)
        #pragma unroll
        for (int n = 0; n < 4; ++n)
          acc[m][n] = __builtin_amdgcn_mfma_f32_16x16x32_bf16(af[m], bfr[n], acc[m][n], 0, 0, 0);
    }
  };

  #define PIPE_BARRIER() do {                                  \
    asm volatile("s_waitcnt lgkmcnt(0)" ::: "memory");         \
    __builtin_amdgcn_s_barrier();                              \
    __builtin_amdgcn_sched_barrier(0);                         \
  } while (0)

  if constexpr (AMODE == 0){
    // R14 proven 2-set loop (fp32 A already reads 256B/row/step)
    loadA(IC<0>{}, kbase); loadB(IC<0>{}, kbase);
    loadA(IC<1>{}, kbase + 64); loadB(IC<1>{}, kbase + 64);
    writeAB(IC<0>{}, 0, kbase);
    PIPE_BARRIER();
    #pragma unroll 1
    for (int s = 0; s < 64; s += 2){
      if (s + 2 < 64){ loadA(IC<0>{}, kbase + (s + 2) * 64); loadB(IC<0>{}, kbase + (s + 2) * 64); }
      compute(0);
      if (s + 1 < 64) writeAB(IC<1>{}, 1, kbase + (s + 1) * 64);
      PIPE_BARRIER();
      if (s + 3 < 64){ loadA(IC<1>{}, kbase + (s + 3) * 64); loadB(IC<1>{}, kbase + (s + 3) * 64); }
      if (s + 1 < 64) compute(1);
      if (s + 2 < 64) writeAB(IC<0>{}, 0, kbase + (s + 2) * 64);
      PIPE_BARRIER();
    }
  } else {
    // 4-set pair-issue loop: A loads for two CONSECUTIVE k-steps issue adjacently
    loadA(IC<0>{}, kbase); loadA(IC<1>{}, kbase + 64);
    loadB(IC<0>{}, kbase); loadB(IC<1>{}, kbase + 64);
    writeAB(IC<0>{}, 0, kbase);
    PIPE_BARRIER();
    #pragma unroll 1
    for (int s = 0; s < 64; s += 4){
      // qA: pair-load steps s+2,s+3 (sets 2,3); compute s (buf0); stage s+1 -> buf1
      loadA(IC<2>{}, kbase + (s + 2) * 64); loadA(IC<3>{}, kbase + (s + 3) * 64);
      loadB(IC<2>{}, kbase + (s + 2) * 64); loadB(IC<3>{}, kbase + (s + 3) * 64);
      compute(0);
      writeAB(IC<1>{}, 1, kbase + (s + 1) * 64);
      PIPE_BARRIER();
      // qB: compute s+1 (buf1); stage s+2 -> buf0
      compute(1);
      writeAB(IC<2>{}, 0, kbase + (s + 2) * 64);
      PIPE_BARRIER();
      // qC: pair-load steps s+4,s+5 (sets 0,1); compute s+2 (buf0); stage s+3 -> buf1
      if (s + 4 < 64){
        loadA(IC<0>{}, kbase + (s + 4) * 64); loadA(IC<1>{}, kbase + (s + 5) * 64);
        loadB(IC<0>{}, kbase + (s + 4) * 64); loadB(IC<1>{}, kbase + (s + 5) * 64);
      }
      compute(0);
      writeAB(IC<3>{}, 1, kbase + (s + 3) * 64);
      PIPE_BARRIER();
      // qD: compute s+3 (buf1); stage s+4 -> buf0
      compute(1);
      if (s + 4 < 64) writeAB(IC<0>{}, 0, kbase + (s + 4) * 64);
      PIPE_BARRIER();
    }
  }
  #undef PIPE_BARRIER

  // epilogue: fp32 partial store (nt), INTERLEAVED: P[row][kc][64]
  #pragma unroll
  for (int m = 0; m < 4; ++m){
    int rowb = row0 + wm * 64 + m * 16 + fq * 4;
    #pragma unroll
    for (int n = 0; n < 4; ++n){
      int col = wn * 64 + n * 16 + fr;
      #pragma unroll
      for (int j = 0; j < 4; ++j)
        __builtin_nontemporal_store(acc[m][n][j],
          &Pdst[(size_t)(rowb + j) * 1024 + kc * 256 + col]);
    }
  }
}

// ---------------- Small GEMM: C[M,BN] = A[M,Kd] @ B^T, BM=32 ----------------
// AMODE: 2 = A bf16 + gather | 3 = A = sum of 4 fp32 partials (INTERLEAVED P[row][4][256])
// EPI: 1 = bias+relu bf16 TRANSPOSED | 2 = bias+relu bf16 row-major | 3 = bias+relu fp32
template<int BN, int AMODE, int EPI>
__global__ __launch_bounds__(512, 2)
void gemm_k(const void* __restrict__ Asrc, const unsigned short* __restrict__ Bsrc,
            const float* __restrict__ bias, const int* __restrict__ gidx,
            void* __restrict__ Cdst, const int M, const int Kd)
{
  constexpr int NF = BN / 64;
  constexpr int BITER = BN / 64;
  __shared__ __align__(16) unsigned short Alds[2][32 * 64];
  __shared__ __align__(16) unsigned short Blds[2][BN * 64];

  const int tid  = threadIdx.x;
  const int lane = tid & 63;
  const int wv   = tid >> 6;
  const int wm   = wv >> 2;
  const int wn   = wv & 3;
  const int row0 = blockIdx.x * 32;
  const int fr = lane & 15, fq = lane >> 4;

  const int rA = tid >> 4;
  const int cA = tid & 15;
  const int rB = tid >> 3;
  const int cB = tid & 7;

  size_t arow;
  if (AMODE == 2) arow = (size_t)gidx[row0 + rA];
  else            arow = (size_t)(row0 + rA);

  f32x4 acc[NF];
  #pragma unroll
  for (int n = 0; n < NF; ++n) acc[n] = f32x4{0.f, 0.f, 0.f, 0.f};

  f32x4 aP[2][4]; s16x4 aB[2]; s16x8 bRg[2][BITER];

  auto loadAB = [&](auto rsc, int k0){
    constexpr int RS = decltype(rsc)::v;
    if constexpr (AMODE == 3){
      #pragma unroll
      for (int q = 0; q < 4; ++q)
        aP[RS][q] = __builtin_nontemporal_load(
          (const f32x4*)((const float*)Asrc + arow * 1024 + q * 256 + (k0 + cA * 4)));
    } else {
      aB[RS] = *(const s16x4*)((const unsigned short*)Asrc + arow * (size_t)Kd + (k0 + cA * 4));
    }
    #pragma unroll
    for (int i = 0; i < BITER; ++i)
      bRg[RS][i] = *(const s16x8*)(Bsrc + (size_t)(rB + i * 64) * Kd + (k0 + cB * 8));
  };

  auto writeAB = [&](auto rsc, int buf){
    constexpr int RS = decltype(rsc)::v;
    s16x4 w;
    if constexpr (AMODE == 3){
      #pragma unroll
      for (int e = 0; e < 4; ++e)
        w[e] = (short)f2bf(aP[RS][0][e] + aP[RS][1][e] + aP[RS][2][e] + aP[RS][3][e]);
    } else {
      w = aB[RS];
    }
    *(s16x4*)&Alds[buf][rA * 64 + ((((cA >> 1) ^ (rA & 7)) * 8) + (cA & 1) * 4)] = w;
    #pragma unroll
    for (int i = 0; i < BITER; ++i){
      int r = rB + i * 64;
      *(s16x8*)&Blds[buf][r * 64 + ((cB ^ (r & 7)) * 8)] = bRg[RS][i];
    }
  };

  auto compute = [&](int buf){
    s16x8 af[2]; s16x8 bfr[NF][2];
    #pragma unroll
    for (int k = 0; k < 2; ++k){
      int row = wm * 16 + fr;
      int c = k * 4 + fq;
      af[k] = *(const s16x8*)&Alds[buf][row * 64 + ((c ^ (row & 7)) * 8)];
    }
    #pragma unroll
    for (int n = 0; n < NF; ++n)
      #pragma unroll
      for (int k = 0; k < 2; ++k){
        int col = wn * (BN / 4) + n * 16 + fr;
        int c = k * 4 + fq;
        bfr[n][k] = *(const s16x8*)&Blds[buf][col * 64 + ((c ^ (col & 7)) * 8)];
      }
    #pragma unroll
    for (int k = 0; k < 2; ++k)
      #pragma unroll
      for (int n = 0; n < NF; ++n)
        acc[n] = __builtin_amdgcn_mfma_f32_16x16x32_bf16(af[k], bfr[n][k], acc[n], 0, 0, 0);
  };

  const int nsteps = Kd / 64;
  loadAB(IC<0>{}, 0);
  loadAB(IC<1>{}, 64);
  writeAB(IC<0>{}, 0);
  __syncthreads();

  for (int s = 0; s < nsteps; s += 2){
    if (s + 2 < nsteps) loadAB(IC<0>{}, (s + 2) * 64);
    compute(0);
    if (s + 1 < nsteps) writeAB(IC<1>{}, 1);
    __syncthreads();
    if (s + 3 < nsteps) loadAB(IC<1>{}, (s + 3) * 64);
    compute(1);
    if (s + 2 < nsteps) writeAB(IC<0>{}, 0);
    __syncthreads();
  }

  {
    int rowb = row0 + wm * 16 + fq * 4;
    #pragma unroll
    for (int n = 0; n < NF; ++n){
      int col = wn * (BN / 4) + n * 16 + fr;
      f32x4 v = acc[n];
      float b = bias[col];
      if constexpr (EPI == 1){
        u16x4 w;
        #pragma unroll
        for (int j = 0; j < 4; ++j) w[j] = f2bf(fmaxf(v[j] + b, 0.f));
        *(u16x4*)((unsigned short*)Cdst + (size_t)col * M + rowb) = w;
      } else if constexpr (EPI == 2){
        unsigned short* o = (unsigned short*)Cdst;
        #pragma unroll
        for (int j = 0; j < 4; ++j) o[(size_t)(rowb + j) * BN + col] = f2bf(fmaxf(v[j] + b, 0.f));
      } else {
        float* o = (float*)Cdst;
        #pragma unroll
        for (int j = 0; j < 4; ++j) o[(size_t)(rowb + j) * BN + col] = fmaxf(v[j] + b, 0.f);
      }
    }
  }
}

// out[i] = softmax(encode[i] @ W2^T + b2), one wave per row
__global__ void mlp2_k(const float* __restrict__ enc, const float* __restrict__ W2,
                       const float* __restrict__ b2, float* __restrict__ out){
  int gw = (int)((blockIdx.x * blockDim.x + threadIdx.x) >> 6);
  int lane = threadIdx.x & 63;
  if (gw >= 8192) return;
  int c = lane & 15, q = lane >> 4;
  const float* e = enc + (size_t)gw * 128 + q * 32;
  const float* w = W2 + c * 128 + q * 32;
  float s = 0.f;
  #pragma unroll
  for (int k = 0; k < 32; ++k) s += e[k] * w[k];
  s += __shfl_xor(s, 16);
  s += __shfl_xor(s, 32);
  s += b2[c];
  float mx = s;
  #pragma unroll
  for (int d = 1; d < 16; d <<= 1) mx = fmaxf(mx, __shfl_xor(mx, d));
  float ex = __expf(s - mx);
  float sm = ex;
  #pragma unroll
  for (int d = 1; d < 16; d <<= 1) sm += __shfl_xor(sm, d);
  float r = ex / sm;
  if (q == 0) out[(size_t)gw * 16 + c] = r;
}

extern "C" void kernel_launch(void* const* d_in, const int* in_sizes, int n_in,
                              void* d_out, int out_size, void* d_ws, size_t ws_size,
                              hipStream_t stream) {
  const float* A  = (const float*)d_in[0];   // [16384,16384]
  const float* x0 = (const float*)d_in[1];   // [16384,256]
  const float* gw = (const float*)d_in[2];   // [3,256,256]
  const float* gb = (const float*)d_in[3];   // [3,256]
  const float* w1 = (const float*)d_in[4];   // [128,256]
  const float* b1 = (const float*)d_in[5];   // [128]
  const float* w2 = (const float*)d_in[6];   // [16,128]
  const float* b2 = (const float*)d_in[7];   // [16]
  const int*  idx = (const int*)d_in[8];     // [8192]
  float* out = (float*)d_out;

  char* ws = (char*)d_ws;
  unsigned short* Abf = (unsigned short*)ws;                        // 16384^2 bf16 (512 MiB)
  float*          P   = (float*)(ws + (512u << 20));                // 16384 x [4 x 256] f32 interleaved (64 MiB)
  unsigned short* xbT = (unsigned short*)(ws + (576u << 20));       // 256*16384 bf16 (8 MiB)
  unsigned short* x3b = (unsigned short*)(ws + (584u << 20));       // 8192*256 bf16
  unsigned short* wgb = (unsigned short*)(ws + (592u << 20));       // 3*256*256 bf16
  unsigned short* w1b = (unsigned short*)(ws + (592u << 20) + 3 * 65536 * 2); // 128*256 bf16
  int* ulist = (int*)(ws + (600u << 20));                           // 8192 ints
  int* gidx2 = (int*)(ws + (600u << 20) + (32u << 10));             // 8192 ints
  int* ucnt  = (int*)(ws + (600u << 20) + (64u << 10));             // 1 int

  xpose_cvt<<<dim3(256, 4), 256, 0, stream>>>(x0, xbT);
  cvt2_k<<<224, 256, 0, stream>>>(gw, wgb, w1, w1b);
  dedup_all<<<1, 1024, 0, stream>>>(idx, ulist, gidx2, ucnt);

  // layer 0: P = A @ X (split-K=4, fp32 A converted + persisted to Abf)
  gemmP_k<0><<<512, 512, 0, stream>>>(A, xbT, P, Abf, nullptr, nullptr);
  gemm_k<256, 3, 1><<<512, 512, 0, stream>>>(P, wgb + 0 * 65536, gb + 0 * 256, nullptr, xbT, 16384, 256);
  // layer 1
  gemmP_k<1><<<512, 512, 0, stream>>>(Abf, xbT, P, nullptr, nullptr, nullptr);
  gemm_k<256, 3, 1><<<512, 512, 0, stream>>>(P, wgb + 1 * 65536, gb + 1 * 256, nullptr, xbT, 16384, 256);
  // layer 2: only unique gathered rows j -> P rows j
  gemmP_k<2><<<256, 512, 0, stream>>>(Abf, xbT, P, nullptr, ulist, ucnt);
  gemm_k<256, 3, 2><<<256, 512, 0, stream>>>(P, wgb + 2 * 65536, gb + 2 * 256, nullptr, x3b, 8192, 256);
  // encode = relu(x3b[rank[idx]] @ W1^T + b1) -> d_out fp32
  gemm_k<128, 2, 3><<<256, 512, 0, stream>>>(x3b, w1b, b1, gidx2, out, 8192, 256);
  // out = softmax(encode @ W2^T + b2)
  mlp2_k<<<2048, 256, 0, stream>>>(out, w2, b2, out + (size_t)8192 * 128);
}

// Round 16
// 767.447 us; speedup vs baseline: 27.1599x; 1.0006x over previous
//
#include <hip/hip_runtime.h>

typedef __attribute__((ext_vector_type(8))) short s16x8;
typedef __attribute__((ext_vector_type(4))) short s16x4;
typedef __attribute__((ext_vector_type(4))) float f32x4;
typedef __attribute__((ext_vector_type(4))) unsigned short u16x4;

template<int V> struct IC { static constexpr int v = V; };

__device__ __forceinline__ unsigned short f2bf(float f){
  unsigned u = __float_as_uint(f);
  u += 0x7fffu + ((u >> 16) & 1u);   // RNE
  return (unsigned short)(u >> 16);
}

// x0 [16384,256] f32 -> XT [256,16384] bf16
__global__ void xpose_cvt(const float* __restrict__ src, unsigned short* __restrict__ dst){
  __shared__ float tile[64][65];
  const int R0 = blockIdx.x * 64;
  const int C0 = blockIdx.y * 64;
  const int t = threadIdx.x;
  #pragma unroll
  for (int i = 0; i < 16; ++i){
    int id = i * 256 + t; int r = id >> 6, c = id & 63;
    tile[r][c] = src[(size_t)(R0 + r) * 256 + (C0 + c)];
  }
  __syncthreads();
  #pragma unroll
  for (int i = 0; i < 16; ++i){
    int id = i * 256 + t; int c = id >> 6, r = id & 63;
    dst[(size_t)(C0 + c) * 16384 + (R0 + r)] = f2bf(tile[r][c]);
  }
}

// merged weight conversion: gw (3*256*256) -> wgb, w1 (128*256) -> w1b
__global__ void cvt2_k(const float* __restrict__ gw, unsigned short* __restrict__ wgb,
                       const float* __restrict__ w1, unsigned short* __restrict__ w1b){
  int i = (blockIdx.x * 256 + threadIdx.x) * 4;
  const int n0 = 3 * 65536;
  if (i < n0){
    f32x4 v = *(const f32x4*)(gw + i);
    u16x4 o; o[0] = f2bf(v[0]); o[1] = f2bf(v[1]); o[2] = f2bf(v[2]); o[3] = f2bf(v[3]);
    *(u16x4*)(wgb + i) = o;
  } else {
    int j = i - n0;
    if (j < 128 * 256){
      f32x4 v = *(const f32x4*)(w1 + j);
      u16x4 o; o[0] = f2bf(v[0]); o[1] = f2bf(v[1]); o[2] = f2bf(v[2]); o[3] = f2bf(v[3]);
      *(u16x4*)(w1b + j) = o;
    }
  }
}

// single-block dedup: flags+scan+compact+remap all in LDS (replaces 4 kernels)
__global__ __launch_bounds__(1024)
void dedup_all(const int* __restrict__ idx, int* __restrict__ ulist,
               int* __restrict__ gidx2, int* __restrict__ ucnt){
  __shared__ unsigned char flags[16384];
  __shared__ unsigned short rank16[16384];
  __shared__ int wsum[16];
  const int t = threadIdx.x;
  #pragma unroll
  for (int i = 0; i < 16; ++i) flags[t + i * 1024] = 0;
  __syncthreads();
  for (int i = t; i < 8192; i += 1024) flags[idx[i]] = 1;   // racing stores of 1: benign
  __syncthreads();
  const int base = t * 16;
  int cnt = 0;
  #pragma unroll
  for (int i = 0; i < 16; ++i) cnt += flags[base + i];
  int lane = t & 63, wv = t >> 6;
  int inc = cnt;
  #pragma unroll
  for (int d = 1; d < 64; d <<= 1){
    int v = __shfl_up(inc, d);
    if (lane >= d) inc += v;
  }
  if (lane == 63) wsum[wv] = inc;
  __syncthreads();
  int woff = 0;
  for (int w = 0; w < wv; ++w) woff += wsum[w];
  int r = woff + inc - cnt;          // exclusive prefix
  #pragma unroll
  for (int i = 0; i < 16; ++i){
    if (flags[base + i]){ rank16[base + i] = (unsigned short)r; ulist[r] = base + i; ++r; }
  }
  if (t == 1023) *ucnt = woff + inc;
  __syncthreads();
  for (int i = t; i < 8192; i += 1024) gidx2[i] = (int)rank16[idx[i]];
}

// ---------------- Pipelined big GEMM: P = A @ X^T (split-K=4, P interleaved) ----------------
// R14 no-vmcnt-drain pipeline. P layout: P[row][kc][64] (kc INNER) so consumers read a
// row's 4 partials from one 4KB page. bf16 modes use 4 register sets with K-PAIR issue:
// loads for steps s+2,s+3 go back-to-back -> 256B contiguous per A-row per DRAM burst
// (halves page activates; the R4-R14 3.5TB/s plateau is activate-limited, 128B/row/step).
// BM=128/BN=256/BK=64, 512 thr (8 waves 2m x 4n), dbuf LDS 96 KiB (1 blk/CU).
// Grid: xcd=b&7; kc=xcd>>1 (B-slice 2 MiB/XCD L2-resident); mi=(xcd&1)*{64|32}+(b>>3).
// AMODE 0: A fp32 (256B/row already), 2-set R14 loop, convert + persist bf16 to Aout.
// AMODE 1: A bf16, 4-set pair-issue (grid 512). AMODE 2: + gather via ulist (grid 256).
template<int AMODE>
__global__ __launch_bounds__(512, 2)
void gemmP_k(const void* __restrict__ Asrc, const unsigned short* __restrict__ Bsrc,
             float* __restrict__ Pdst, unsigned short* __restrict__ Aout,
             const int* __restrict__ ulist, const int* __restrict__ pnuniq)
{
  __shared__ __align__(16) unsigned short Alds[2][128 * 64];
  __shared__ __align__(16) unsigned short Blds[2][256 * 64];

  const int tid  = threadIdx.x;
  const int lane = tid & 63;
  const int wv   = tid >> 6;
  const int wm   = wv >> 2;        // 0..1 (64 rows each)
  const int wn   = wv & 3;         // 0..3 (64 cols each)
  const int fr = lane & 15, fq = lane >> 4;

  const int b    = blockIdx.x;
  const int xcd  = b & 7;
  const int kc   = xcd >> 1;                    // 0..3
  const int mi   = (AMODE == 2) ? (((xcd & 1) << 5) + (b >> 3))
                                 : (((xcd & 1) << 6) + (b >> 3));
  const int row0 = mi * 128;
  const int kbase = kc * 4096;

  int nuniq = 0;
  if constexpr (AMODE == 2){
    nuniq = *pnuniq;
    if (row0 >= nuniq) return;     // block-uniform early exit before any barrier
  }

  const int rS = tid >> 3;         // 0..63 (staging row base)
  const int cS = tid & 7;          // 16B chunk within 64-elem k-slab

  size_t ar0, ar1;
  if constexpr (AMODE == 2){
    int j0 = row0 + rS, j1 = row0 + rS + 64;
    ar0 = (size_t)ulist[j0 < nuniq ? j0 : 0];
    ar1 = (size_t)ulist[j1 < nuniq ? j1 : 0];
  } else {
    ar0 = (size_t)(row0 + rS);
    ar1 = (size_t)(row0 + rS + 64);
  }

  f32x4 acc[4][4];
  #pragma unroll
  for (int m = 0; m < 4; ++m)
    #pragma unroll
    for (int n = 0; n < 4; ++n)
      acc[m][n] = f32x4{0.f, 0.f, 0.f, 0.f};

  // statically-indexed staging sets (IC<> -> registers, rule #20)
  f32x4 aF[2][4];    // AMODE 0 (2 sets)
  s16x8 aB[4][2];    // AMODE 1/2 (4 sets)
  s16x8 bR[4][4];

  auto loadA = [&](auto setc, int k0){
    constexpr int S = decltype(setc)::v;
    if constexpr (AMODE == 0){
      const float* p0 = (const float*)Asrc + ar0 * 16384 + k0 + cS * 8;
      const float* p1 = (const float*)Asrc + ar1 * 16384 + k0 + cS * 8;
      aF[S][0] = __builtin_nontemporal_load((const f32x4*)p0);
      aF[S][1] = __builtin_nontemporal_load((const f32x4*)(p0 + 4));
      aF[S][2] = __builtin_nontemporal_load((const f32x4*)p1);
      aF[S][3] = __builtin_nontemporal_load((const f32x4*)(p1 + 4));
    } else {
      aB[S][0] = __builtin_nontemporal_load(
        (const s16x8*)((const unsigned short*)Asrc + ar0 * 16384 + k0 + cS * 8));
      aB[S][1] = __builtin_nontemporal_load(
        (const s16x8*)((const unsigned short*)Asrc + ar1 * 16384 + k0 + cS * 8));
    }
  };
  auto loadB = [&](auto setc, int k0){
    constexpr int S = decltype(setc)::v;
    #pragma unroll
    for (int i = 0; i < 4; ++i)
      bR[S][i] = *(const s16x8*)(Bsrc + (size_t)(rS + i * 64) * 16384 + k0 + cS * 8);
  };

  auto writeAB = [&](auto setc, int buf, int k0){
    constexpr int S = decltype(setc)::v;
    s16x8 w0, w1;
    if constexpr (AMODE == 0){
      constexpr int S2 = (S < 2) ? S : 0;
      #pragma unroll
      for (int e = 0; e < 4; ++e){
        w0[e] = (short)f2bf(aF[S2][0][e]); w0[e + 4] = (short)f2bf(aF[S2][1][e]);
        w1[e] = (short)f2bf(aF[S2][2][e]); w1[e + 4] = (short)f2bf(aF[S2][3][e]);
      }
      __builtin_nontemporal_store(w0, (s16x8*)&Aout[ar0 * 16384 + k0 + cS * 8]);
      __builtin_nontemporal_store(w1, (s16x8*)&Aout[ar1 * 16384 + k0 + cS * 8]);
    } else {
      w0 = aB[S][0];
      w1 = aB[S][1];
    }
    *(s16x8*)&Alds[buf][rS * 64 + ((cS ^ (rS & 7)) * 8)] = w0;
    *(s16x8*)&Alds[buf][(rS + 64) * 64 + ((cS ^ (rS & 7)) * 8)] = w1;
    #pragma unroll
    for (int i = 0; i < 4; ++i){
      int r = rS + i * 64;
      *(s16x8*)&Blds[buf][r * 64 + ((cS ^ (r & 7)) * 8)] = bR[S][i];
    }
  };

  auto compute = [&](int buf){
    #pragma unroll
    for (int k = 0; k < 2; ++k){
      s16x8 af[4], bfr[4];
      const int c = k * 4 + fq;
      #pragma unroll
      for (int m = 0; m < 4; ++m){
        int row = wm * 64 + m * 16 + fr;
        af[m] = *(const s16x8*)&Alds[buf][row * 64 + ((c ^ (row & 7)) * 8)];
      }
      #pragma unroll
      for (int n = 0; n < 4; ++n){
        int col = wn * 64 + n * 16 + fr;
        bfr[n] = *(const s16x8*)&Blds[buf][col * 64 + ((c ^ (col & 7)) * 8)];
      }
      #pragma unroll
      for (int m = 0; m < 4; ++m)
        #pragma unroll
        for (int n = 0; n < 4; ++n)
          acc[m][n] = __builtin_amdgcn_mfma_f32_16x16x32_bf16(af[m], bfr[n], acc[m][n], 0, 0, 0);
    }
  };

  #define PIPE_BARRIER() do {                                  \
    asm volatile("s_waitcnt lgkmcnt(0)" ::: "memory");         \
    __builtin_amdgcn_s_barrier();                              \
    __builtin_amdgcn_sched_barrier(0);                         \
  } while (0)

  if constexpr (AMODE == 0){
    // R14 proven 2-set loop (fp32 A already reads 256B/row/step)
    loadA(IC<0>{}, kbase); loadB(IC<0>{}, kbase);
    loadA(IC<1>{}, kbase + 64); loadB(IC<1>{}, kbase + 64);
    writeAB(IC<0>{}, 0, kbase);
    PIPE_BARRIER();
    #pragma unroll 1
    for (int s = 0; s < 64; s += 2){
      if (s + 2 < 64){ loadA(IC<0>{}, kbase + (s + 2) * 64); loadB(IC<0>{}, kbase + (s + 2) * 64); }
      compute(0);
      if (s + 1 < 64) writeAB(IC<1>{}, 1, kbase + (s + 1) * 64);
      PIPE_BARRIER();
      if (s + 3 < 64){ loadA(IC<1>{}, kbase + (s + 3) * 64); loadB(IC<1>{}, kbase + (s + 3) * 64); }
      if (s + 1 < 64) compute(1);
      if (s + 2 < 64) writeAB(IC<0>{}, 0, kbase + (s + 2) * 64);
      PIPE_BARRIER();
    }
  } else {
    // 4-set pair-issue loop: A loads for two CONSECUTIVE k-steps issue adjacently
    loadA(IC<0>{}, kbase); loadA(IC<1>{}, kbase + 64);
    loadB(IC<0>{}, kbase); loadB(IC<1>{}, kbase + 64);
    writeAB(IC<0>{}, 0, kbase);
    PIPE_BARRIER();
    #pragma unroll 1
    for (int s = 0; s < 64; s += 4){
      // qA: pair-load steps s+2,s+3 (sets 2,3); compute s (buf0); stage s+1 -> buf1
      loadA(IC<2>{}, kbase + (s + 2) * 64); loadA(IC<3>{}, kbase + (s + 3) * 64);
      loadB(IC<2>{}, kbase + (s + 2) * 64); loadB(IC<3>{}, kbase + (s + 3) * 64);
      compute(0);
      writeAB(IC<1>{}, 1, kbase + (s + 1) * 64);
      PIPE_BARRIER();
      // qB: compute s+1 (buf1); stage s+2 -> buf0
      compute(1);
      writeAB(IC<2>{}, 0, kbase + (s + 2) * 64);
      PIPE_BARRIER();
      // qC: pair-load steps s+4,s+5 (sets 0,1); compute s+2 (buf0); stage s+3 -> buf1
      if (s + 4 < 64){
        loadA(IC<0>{}, kbase + (s + 4) * 64); loadA(IC<1>{}, kbase + (s + 5) * 64);
        loadB(IC<0>{}, kbase + (s + 4) * 64); loadB(IC<1>{}, kbase + (s + 5) * 64);
      }
      compute(0);
      writeAB(IC<3>{}, 1, kbase + (s + 3) * 64);
      PIPE_BARRIER();
      // qD: compute s+3 (buf1); stage s+4 -> buf0
      compute(1);
      if (s + 4 < 64) writeAB(IC<0>{}, 0, kbase + (s + 4) * 64);
      PIPE_BARRIER();
    }
  }
  #undef PIPE_BARRIER

  // epilogue: fp32 partial store (nt), INTERLEAVED: P[row][kc][64]
  #pragma unroll
  for (int m = 0; m < 4; ++m){
    int rowb = row0 + wm * 64 + m * 16 + fq * 4;
    #pragma unroll
    for (int n = 0; n < 4; ++n){
      int col = wn * 64 + n * 16 + fr;
      #pragma unroll
      for (int j = 0; j < 4; ++j)
        __builtin_nontemporal_store(acc[m][n][j],
          &Pdst[(size_t)(rowb + j) * 1024 + kc * 256 + col]);
    }
  }
}

// ---------------- Small GEMM: C[M,BN] = A[M,Kd] @ B^T, BM=32 ----------------
// AMODE: 2 = A bf16 + gather | 3 = A = sum of 4 fp32 partials (INTERLEAVED P[row][4][256])
// EPI: 1 = bias+relu bf16 TRANSPOSED | 2 = bias+relu bf16 row-major | 3 = bias+relu fp32
template<int BN, int AMODE, int EPI>
__global__ __launch_bounds__(512, 2)
void gemm_k(const void* __restrict__ Asrc, const unsigned short* __restrict__ Bsrc,
            const float* __restrict__ bias, const int* __restrict__ gidx,
            void* __restrict__ Cdst, const int M, const int Kd)
{
  constexpr int NF = BN / 64;
  constexpr int BITER = BN / 64;
  __shared__ __align__(16) unsigned short Alds[2][32 * 64];
  __shared__ __align__(16) unsigned short Blds[2][BN * 64];

  const int tid  = threadIdx.x;
  const int lane = tid & 63;
  const int wv   = tid >> 6;
  const int wm   = wv >> 2;
  const int wn   = wv & 3;
  const int row0 = blockIdx.x * 32;
  const int fr = lane & 15, fq = lane >> 4;

  const int rA = tid >> 4;
  const int cA = tid & 15;
  const int rB = tid >> 3;
  const int cB = tid & 7;

  size_t arow;
  if (AMODE == 2) arow = (size_t)gidx[row0 + rA];
  else            arow = (size_t)(row0 + rA);

  f32x4 acc[NF];
  #pragma unroll
  for (int n = 0; n < NF; ++n) acc[n] = f32x4{0.f, 0.f, 0.f, 0.f};

  f32x4 aP[2][4]; s16x4 aB[2]; s16x8 bRg[2][BITER];

  auto loadAB = [&](auto rsc, int k0){
    constexpr int RS = decltype(rsc)::v;
    if constexpr (AMODE == 3){
      #pragma unroll
      for (int q = 0; q < 4; ++q)
        aP[RS][q] = __builtin_nontemporal_load(
          (const f32x4*)((const float*)Asrc + arow * 1024 + q * 256 + (k0 + cA * 4)));
    } else {
      aB[RS] = *(const s16x4*)((const unsigned short*)Asrc + arow * (size_t)Kd + (k0 + cA * 4));
    }
    #pragma unroll
    for (int i = 0; i < BITER; ++i)
      bRg[RS][i] = *(const s16x8*)(Bsrc + (size_t)(rB + i * 64) * Kd + (k0 + cB * 8));
  };

  auto writeAB = [&](auto rsc, int buf){
    constexpr int RS = decltype(rsc)::v;
    s16x4 w;
    if constexpr (AMODE == 3){
      #pragma unroll
      for (int e = 0; e < 4; ++e)
        w[e] = (short)f2bf(aP[RS][0][e] + aP[RS][1][e] + aP[RS][2][e] + aP[RS][3][e]);
    } else {
      w = aB[RS];
    }
    *(s16x4*)&Alds[buf][rA * 64 + ((((cA >> 1) ^ (rA & 7)) * 8) + (cA & 1) * 4)] = w;
    #pragma unroll
    for (int i = 0; i < BITER; ++i){
      int r = rB + i * 64;
      *(s16x8*)&Blds[buf][r * 64 + ((cB ^ (r & 7)) * 8)] = bRg[RS][i];
    }
  };

  auto compute = [&](int buf){
    s16x8 af[2]; s16x8 bfr[NF][2];
    #pragma unroll
    for (int k = 0; k < 2; ++k){
      int row = wm * 16 + fr;
      int c = k * 4 + fq;
      af[k] = *(const s16x8*)&Alds[buf][row * 64 + ((c ^ (row & 7)) * 8)];
    }
    #pragma unroll
    for (int n = 0; n < NF; ++n)
      #pragma unroll
      for (int k = 0; k < 2; ++k){
        int col = wn * (BN / 4) + n * 16 + fr;
        int c = k * 4 + fq;
        bfr[n][k] = *(const s16x8*)&Blds[buf][col * 64 + ((c ^ (col & 7)) * 8)];
      }
    #pragma unroll
    for (int k = 0; k < 2; ++k)
      #pragma unroll
      for (int n = 0; n < NF; ++n)
        acc[n] = __builtin_amdgcn_mfma_f32_16x16x32_bf16(af[k], bfr[n][k], acc[n], 0, 0, 0);
  };

  const int nsteps = Kd / 64;
  loadAB(IC<0>{}, 0);
  loadAB(IC<1>{}, 64);
  writeAB(IC<0>{}, 0);
  __syncthreads();

  for (int s = 0; s < nsteps; s += 2){
    if (s + 2 < nsteps) loadAB(IC<0>{}, (s + 2) * 64);
    compute(0);
    if (s + 1 < nsteps) writeAB(IC<1>{}, 1);
    __syncthreads();
    if (s + 3 < nsteps) loadAB(IC<1>{}, (s + 3) * 64);
    compute(1);
    if (s + 2 < nsteps) writeAB(IC<0>{}, 0);
    __syncthreads();
  }

  {
    int rowb = row0 + wm * 16 + fq * 4;
    #pragma unroll
    for (int n = 0; n < NF; ++n){
      int col = wn * (BN / 4) + n * 16 + fr;
      f32x4 v = acc[n];
      float b = bias[col];
      if constexpr (EPI == 1){
        u16x4 w;
        #pragma unroll
        for (int j = 0; j < 4; ++j) w[j] = f2bf(fmaxf(v[j] + b, 0.f));
        *(u16x4*)((unsigned short*)Cdst + (size_t)col * M + rowb) = w;
      } else if constexpr (EPI == 2){
        unsigned short* o = (unsigned short*)Cdst;
        #pragma unroll
        for (int j = 0; j < 4; ++j) o[(size_t)(rowb + j) * BN + col] = f2bf(fmaxf(v[j] + b, 0.f));
      } else {
        float* o = (float*)Cdst;
        #pragma unroll
        for (int j = 0; j < 4; ++j) o[(size_t)(rowb + j) * BN + col] = fmaxf(v[j] + b, 0.f);
      }
    }
  }
}

// out[i] = softmax(encode[i] @ W2^T + b2), one wave per row
__global__ void mlp2_k(const float* __restrict__ enc, const float* __restrict__ W2,
                       const float* __restrict__ b2, float* __restrict__ out){
  int gw = (int)((blockIdx.x * blockDim.x + threadIdx.x) >> 6);
  int lane = threadIdx.x & 63;
  if (gw >= 8192) return;
  int c = lane & 15, q = lane >> 4;
  const float* e = enc + (size_t)gw * 128 + q * 32;
  const float* w = W2 + c * 128 + q * 32;
  float s = 0.f;
  #pragma unroll
  for (int k = 0; k < 32; ++k) s += e[k] * w[k];
  s += __shfl_xor(s, 16);
  s += __shfl_xor(s, 32);
  s += b2[c];
  float mx = s;
  #pragma unroll
  for (int d = 1; d < 16; d <<= 1) mx = fmaxf(mx, __shfl_xor(mx, d));
  float ex = __expf(s - mx);
  float sm = ex;
  #pragma unroll
  for (int d = 1; d < 16; d <<= 1) sm += __shfl_xor(sm, d);
  float r = ex / sm;
  if (q == 0) out[(size_t)gw * 16 + c] = r;
}

extern "C" void kernel_launch(void* const* d_in, const int* in_sizes, int n_in,
                              void* d_out, int out_size, void* d_ws, size_t ws_size,
                              hipStream_t stream) {
  const float* A  = (const float*)d_in[0];   // [16384,16384]
  const float* x0 = (const float*)d_in[1];   // [16384,256]
  const float* gw = (const float*)d_in[2];   // [3,256,256]
  const float* gb = (const float*)d_in[3];   // [3,256]
  const float* w1 = (const float*)d_in[4];   // [128,256]
  const float* b1 = (const float*)d_in[5];   // [128]
  const float* w2 = (const float*)d_in[6];   // [16,128]
  const float* b2 = (const float*)d_in[7];   // [16]
  const int*  idx = (const int*)d_in[8];     // [8192]
  float* out = (float*)d_out;

  char* ws = (char*)d_ws;
  unsigned short* Abf = (unsigned short*)ws;                        // 16384^2 bf16 (512 MiB)
  float*          P   = (float*)(ws + (512u << 20));                // 16384 x [4 x 256] f32 interleaved (64 MiB)
  unsigned short* xbT = (unsigned short*)(ws + (576u << 20));       // 256*16384 bf16 (8 MiB)
  unsigned short* x3b = (unsigned short*)(ws + (584u << 20));       // 8192*256 bf16
  unsigned short* wgb = (unsigned short*)(ws + (592u << 20));       // 3*256*256 bf16
  unsigned short* w1b = (unsigned short*)(ws + (592u << 20) + 3 * 65536 * 2); // 128*256 bf16
  int* ulist = (int*)(ws + (600u << 20));                           // 8192 ints
  int* gidx2 = (int*)(ws + (600u << 20) + (32u << 10));             // 8192 ints
  int* ucnt  = (int*)(ws + (600u << 20) + (64u << 10));             // 1 int

  xpose_cvt<<<dim3(256, 4), 256, 0, stream>>>(x0, xbT);
  cvt2_k<<<224, 256, 0, stream>>>(gw, wgb, w1, w1b);
  dedup_all<<<1, 1024, 0, stream>>>(idx, ulist, gidx2, ucnt);

  // layer 0: P = A @ X (split-K=4, fp32 A converted + persisted to Abf)
  gemmP_k<0><<<512, 512, 0, stream>>>(A, xbT, P, Abf, nullptr, nullptr);
  gemm_k<256, 3, 1><<<512, 512, 0, stream>>>(P, wgb + 0 * 65536, gb + 0 * 256, nullptr, xbT, 16384, 256);
  // layer 1
  gemmP_k<1><<<512, 512, 0, stream>>>(Abf, xbT, P, nullptr, nullptr, nullptr);
  gemm_k<256, 3, 1><<<512, 512, 0, stream>>>(P, wgb + 1 * 65536, gb + 1 * 256, nullptr, xbT, 16384, 256);
  // layer 2: only unique gathered rows j -> P rows j
  gemmP_k<2><<<256, 512, 0, stream>>>(Abf, xbT, P, nullptr, ulist, ucnt);
  gemm_k<256, 3, 2><<<256, 512, 0, stream>>>(P, wgb + 2 * 65536, gb + 2 * 256, nullptr, x3b, 8192, 256);
  // encode = relu(x3b[rank[idx]] @ W1^T + b1) -> d_out fp32
  gemm_k<128, 2, 3><<<256, 512, 0, stream>>>(x3b, w1b, b1, gidx2, out, 8192, 256);
  // out = softmax(encode @ W2^T + b2)
  mlp2_k<<<2048, 256, 0, stream>>>(out, w2, b2, out + (size_t)8192 * 128);
}